// Round 14
// baseline (161.123 us; speedup 1.0000x reference)
//
#include <hip/hip_runtime.h>

// Problem shapes (fixed by reference setup_inputs)
#define B_DIM 1024
#define C_DIM 128
#define K_DIM 1024
#define E_DIM 4
#define EMBED_ELEMS (B_DIM * C_DIM * E_DIM)

typedef float f32x4 __attribute__((ext_vector_type(4)));

// f32 screen threshold: worst-case |d32 - d64| <= ~1.3e-4; 4e-3 gives 30x
// margin. Rows with top-2 gap <= THR are re-run in exact f64 (R3-proven).
#define SCREEN_THR 4e-3f

// ---------------------------------------------------------------------------
// K_fused: f32-screened argmin + embed + paced 128 KB/block zero-fill.
// Grid = 4096 blocks: covers all (b,c) rows AND all 512 MB of zeros.
// ---------------------------------------------------------------------------
__global__ __launch_bounds__(256) void vq_fused_kernel(
    const float* __restrict__ cw_q,      // (B, C*E) f32
    const float* __restrict__ codebook,  // (C, K, E) f32
    float* __restrict__ out,             // [embed | one_hot]
    int* __restrict__ idx_out)           // (B, C) int32 in d_ws
{
    __shared__ float4 lds_cb[K_DIM];     // 16 KB: codebook[c]

    const int lane = threadIdx.x & 63;
    const int wave = threadIdx.x >> 6;
    const int bid  = blockIdx.x;
    const int c      = bid >> 5;         // 32 blocks per c
    const int btile  = bid & 31;
    const int b_base = btile * 32 + wave * 8;

    const float4* cb4 = (const float4*)codebook + (size_t)c * K_DIM;
    const float4* x4  = (const float4*)cw_q;    // (B, C) float4
    float4* emb4 = (float4*)out;                // (B, C) float4

    // Zero-fill destination: 128 KB contiguous per block.
    f32x4* zdst = (f32x4*)(out + EMBED_ELEMS) + (size_t)bid * 8192
                + threadIdx.x;
    const f32x4 zval = {0.f, 0.f, 0.f, 0.f};

    // Stage codebook into LDS; load this wave's 8 x-rows.
    for (int t = threadIdx.x; t < K_DIM; t += 256)
        lds_cb[t] = cb4[t];
    float4 xr[8];
#pragma unroll
    for (int i = 0; i < 8; ++i)
        xr[i] = x4[(size_t)(b_base + i) * C_DIM + c];
    __syncthreads();

    for (int g = 0; g < 2; ++g) {
        // -2x in f32 (exact scaling).
        float x2f[4][4];
#pragma unroll
        for (int ii = 0; ii < 4; ++ii) {
            const float4 x = xr[g * 4 + ii];
            x2f[ii][0] = -2.0f * x.x;  x2f[ii][1] = -2.0f * x.y;
            x2f[ii][2] = -2.0f * x.z;  x2f[ii][3] = -2.0f * x.w;
        }

        float b1[4], b2[4];  int k1[4];
#pragma unroll
        for (int ii = 0; ii < 4; ++ii) { b1[ii] = INFINITY; b2[ii] = INFINITY; k1[ii] = 0x7fffffff; }

        // f32 screen scan; one paced zero store per j; LDS prefetch.
        float4 cbn = lds_cb[lane];
#pragma unroll 1   // keep one store per iteration — do NOT re-cluster
        for (int j = 0; j < 16; ++j) {
            const float4 cb = cbn;
            if (j < 15) cbn = lds_cb[(j + 1) * 64 + lane];
            zdst[(g * 16 + j) * 256] = zval;   // paced slot g*16+j of 32

            const float bsqj = cb.x * cb.x + cb.y * cb.y
                             + cb.z * cb.z + cb.w * cb.w;
            const int k = j * 64 + lane;
#pragma unroll
            for (int ii = 0; ii < 4; ++ii) {
                const float d = fmaf(cb.w, x2f[ii][3],
                                fmaf(cb.z, x2f[ii][2],
                                fmaf(cb.y, x2f[ii][1],
                                fmaf(cb.x, x2f[ii][0], bsqj))));
                const bool  lt1  = d < b1[ii];
                const float old1 = b1[ii];
                b1[ii] = lt1 ? d : old1;
                k1[ii] = lt1 ? k : k1[ii];
                b2[ii] = lt1 ? old1 : fminf(b2[ii], d);
            }
        }

        // Butterfly: global top-2 values + argmin index (32-bit ops).
#pragma unroll
        for (int off = 32; off >= 1; off >>= 1) {
#pragma unroll
            for (int ii = 0; ii < 4; ++ii) {
                const float ob1 = __shfl_xor(b1[ii], off);
                const int   ok1 = __shfl_xor(k1[ii], off);
                const float ob2 = __shfl_xor(b2[ii], off);
                const float mx  = fmaxf(b1[ii], ob1);
                b2[ii] = fminf(mx, fminf(b2[ii], ob2));
                if (ob1 < b1[ii] || (ob1 == b1[ii] && ok1 < k1[ii])) {
                    b1[ii] = ob1; k1[ii] = ok1;
                }
            }
        }

        // Accept or exact-recheck each row (branch is wave-uniform).
#pragma unroll 1
        for (int ii = 0; ii < 4; ++ii) {
            int fk = k1[ii];
            if (!(b2[ii] - b1[ii] > SCREEN_THR)) {
                // Exact f64 path (bit-identical to R3-proven kernel).
                const float4 x = xr[g * 4 + ii];
                const double x20 = -2.0 * (double)x.x;
                const double x21 = -2.0 * (double)x.y;
                const double x22 = -2.0 * (double)x.z;
                const double x23 = -2.0 * (double)x.w;
                double bd = INFINITY;  int bk = 0x7fffffff;
                for (int j = 0; j < 16; ++j) {
                    const float4 cb = lds_cb[j * 64 + lane];
                    const double bx = (double)cb.x, by = (double)cb.y,
                                 bz = (double)cb.z, bw = (double)cb.w;
                    const double bsqj = bx * bx + by * by + bz * bz + bw * bw;
                    const double d = fma(bw, x23, fma(bz, x22,
                                     fma(by, x21, fma(bx, x20, bsqj))));
                    const int k = j * 64 + lane;
                    if (d < bd) { bd = d; bk = k; }
                }
#pragma unroll
                for (int off = 32; off >= 1; off >>= 1) {
                    const double od = __shfl_xor(bd, off);
                    const int    oi = __shfl_xor(bk, off);
                    if (od < bd || (od == bd && oi < bk)) { bd = od; bk = oi; }
                }
                fk = bk;
            }
            const int b = b_base + g * 4 + ii;
            if (lane == 0) {
                emb4[(size_t)b * C_DIM + c] = lds_cb[fk];
                idx_out[b * C_DIM + c]      = fk;   // K_ones reads it
            }
        }
    }
}

// ---------------------------------------------------------------------------
// K_ones: scatter the 131072 ones. One thread per (b*C+c) row.
// ---------------------------------------------------------------------------
__global__ __launch_bounds__(256) void vq_scatter_ones(
    const int* __restrict__ idx_in,      // (B, C) flat
    float* __restrict__ out)             // one_hot at EMBED_ELEMS
{
    const int r = blockIdx.x * 256 + threadIdx.x;   // flat row, coalesced idx
    const int k = idx_in[r];
    out[EMBED_ELEMS + (size_t)r * K_DIM + k] = 1.0f;
}

extern "C" void kernel_launch(void* const* d_in, const int* in_sizes, int n_in,
                              void* d_out, int out_size, void* d_ws, size_t ws_size,
                              hipStream_t stream) {
    const float* cw_q     = (const float*)d_in[0];
    const float* codebook = (const float*)d_in[1];
    float* out = (float*)d_out;
    int*   idx = (int*)d_ws;   // 512 KB scratch

    vq_fused_kernel<<<C_DIM * (B_DIM / 32), 256, 0, stream>>>(cw_q, codebook, out, idx);
    vq_scatter_ones<<<(B_DIM * C_DIM) / 256, 256, 0, stream>>>(idx, out);
}

// Round 15
// 158.480 us; speedup vs baseline: 1.0167x; 1.0167x over previous
//
#include <hip/hip_runtime.h>

// Problem shapes (fixed by reference setup_inputs)
#define B_DIM 1024
#define C_DIM 128
#define K_DIM 1024
#define E_DIM 4
#define EMBED_ELEMS (B_DIM * C_DIM * E_DIM)

typedef float f32x4 __attribute__((ext_vector_type(4)));

// f32 screen: worst-case |d32 - d64| <= ~1e-4 (11 roundings x |terms|<~150).
// Accept is safe when gap32 > 2e-4; THR = 1e-3 gives 5x margin. Typical
// top-2 gap ~0.1 -> recheck rate ~1% (R14's 4e-3 fired ~30% -> regression).
#define SCREEN_THR 1e-3f

// ---------------------------------------------------------------------------
// K_fused: f32-screened argmin + embed + paced 128 KB/block zero-fill.
// Grid = 4096 blocks: covers all (b,c) rows AND all 512 MB of zeros.
// ---------------------------------------------------------------------------
__global__ __launch_bounds__(256) void vq_fused_kernel(
    const float* __restrict__ cw_q,      // (B, C*E) f32
    const float* __restrict__ codebook,  // (C, K, E) f32
    float* __restrict__ out,             // [embed | one_hot]
    int* __restrict__ idx_out)           // (B, C) int32 in d_ws
{
    __shared__ float4 lds_cb[K_DIM];     // 16 KB: codebook[c]

    const int lane = threadIdx.x & 63;
    const int wave = threadIdx.x >> 6;
    const int bid  = blockIdx.x;
    const int c      = bid >> 5;         // 32 blocks per c
    const int btile  = bid & 31;
    const int b_base = btile * 32 + wave * 8;

    const float4* cb4 = (const float4*)codebook + (size_t)c * K_DIM;
    const float4* x4  = (const float4*)cw_q;    // (B, C) float4
    float4* emb4 = (float4*)out;                // (B, C) float4

    // Zero-fill destination: 128 KB contiguous per block.
    f32x4* zdst = (f32x4*)(out + EMBED_ELEMS) + (size_t)bid * 8192
                + threadIdx.x;
    const f32x4 zval = {0.f, 0.f, 0.f, 0.f};

    // Stage codebook into LDS; load this wave's 8 x-rows.
    for (int t = threadIdx.x; t < K_DIM; t += 256)
        lds_cb[t] = cb4[t];
    float4 xr[8];
#pragma unroll
    for (int i = 0; i < 8; ++i)
        xr[i] = x4[(size_t)(b_base + i) * C_DIM + c];
    __syncthreads();

    // Per-lane ||b_k||^2 in f32, hoisted out of both group loops.
    float bsqf[16];
#pragma unroll
    for (int j = 0; j < 16; ++j) {
        const float4 cb = lds_cb[j * 64 + lane];
        bsqf[j] = cb.x * cb.x + cb.y * cb.y + cb.z * cb.z + cb.w * cb.w;
    }

    for (int g = 0; g < 2; ++g) {
        float x2f[4][4];
#pragma unroll
        for (int ii = 0; ii < 4; ++ii) {
            const float4 x = xr[g * 4 + ii];
            x2f[ii][0] = -2.0f * x.x;  x2f[ii][1] = -2.0f * x.y;
            x2f[ii][2] = -2.0f * x.z;  x2f[ii][3] = -2.0f * x.w;
        }

        float b1[4], b2[4];  int k1[4];
#pragma unroll
        for (int ii = 0; ii < 4; ++ii) { b1[ii] = INFINITY; b2[ii] = INFINITY; k1[ii] = 0x7fffffff; }

        // f32 screen scan; one paced zero store per j; LDS prefetch.
        float4 cbn = lds_cb[lane];
#pragma unroll 1   // keep one store per iteration — do NOT re-cluster
        for (int j = 0; j < 16; ++j) {
            const float4 cb = cbn;
            if (j < 15) cbn = lds_cb[(j + 1) * 64 + lane];
            zdst[(g * 16 + j) * 256] = zval;   // paced slot g*16+j of 32

            const float bsqj = bsqf[j];
            const int k = j * 64 + lane;
#pragma unroll
            for (int ii = 0; ii < 4; ++ii) {
                const float d = fmaf(cb.w, x2f[ii][3],
                                fmaf(cb.z, x2f[ii][2],
                                fmaf(cb.y, x2f[ii][1],
                                fmaf(cb.x, x2f[ii][0], bsqj))));
                const bool  lt1  = d < b1[ii];
                const float old1 = b1[ii];
                b1[ii] = lt1 ? d : old1;
                k1[ii] = lt1 ? k : k1[ii];
                b2[ii] = lt1 ? old1 : fminf(b2[ii], d);
            }
        }

        // Butterfly: global top-2 values + argmin index (32-bit ops).
#pragma unroll
        for (int off = 32; off >= 1; off >>= 1) {
#pragma unroll
            for (int ii = 0; ii < 4; ++ii) {
                const float ob1 = __shfl_xor(b1[ii], off);
                const int   ok1 = __shfl_xor(k1[ii], off);
                const float ob2 = __shfl_xor(b2[ii], off);
                const float mx  = fmaxf(b1[ii], ob1);
                b2[ii] = fminf(mx, fminf(b2[ii], ob2));
                if (ob1 < b1[ii] || (ob1 == b1[ii] && ok1 < k1[ii])) {
                    b1[ii] = ob1; k1[ii] = ok1;
                }
            }
        }

        // Accept or exact-recheck each row (branch is wave-uniform, ~1%).
#pragma unroll 1
        for (int ii = 0; ii < 4; ++ii) {
            int fk = k1[ii];
            if (!(b2[ii] - b1[ii] > SCREEN_THR)) {
                // Exact f64 path (bit-identical to R3-proven kernel).
                const float4 x = xr[g * 4 + ii];
                const double x20 = -2.0 * (double)x.x;
                const double x21 = -2.0 * (double)x.y;
                const double x22 = -2.0 * (double)x.z;
                const double x23 = -2.0 * (double)x.w;
                double bd = INFINITY;  int bk = 0x7fffffff;
                for (int j = 0; j < 16; ++j) {
                    const float4 cb = lds_cb[j * 64 + lane];
                    const double bx = (double)cb.x, by = (double)cb.y,
                                 bz = (double)cb.z, bw = (double)cb.w;
                    const double bsqj = bx * bx + by * by + bz * bz + bw * bw;
                    const double d = fma(bw, x23, fma(bz, x22,
                                     fma(by, x21, fma(bx, x20, bsqj))));
                    const int k = j * 64 + lane;
                    if (d < bd) { bd = d; bk = k; }
                }
#pragma unroll
                for (int off = 32; off >= 1; off >>= 1) {
                    const double od = __shfl_xor(bd, off);
                    const int    oi = __shfl_xor(bk, off);
                    if (od < bd || (od == bd && oi < bk)) { bd = od; bk = oi; }
                }
                fk = bk;
            }
            const int b = b_base + g * 4 + ii;
            if (lane == 0) {
                emb4[(size_t)b * C_DIM + c] = lds_cb[fk];
                idx_out[b * C_DIM + c]      = fk;   // K_ones reads it
            }
        }
    }
}

// ---------------------------------------------------------------------------
// K_ones: scatter the 131072 ones. One thread per (b*C+c) row.
// ---------------------------------------------------------------------------
__global__ __launch_bounds__(256) void vq_scatter_ones(
    const int* __restrict__ idx_in,      // (B, C) flat
    float* __restrict__ out)             // one_hot at EMBED_ELEMS
{
    const int r = blockIdx.x * 256 + threadIdx.x;   // flat row, coalesced idx
    const int k = idx_in[r];
    out[EMBED_ELEMS + (size_t)r * K_DIM + k] = 1.0f;
}

extern "C" void kernel_launch(void* const* d_in, const int* in_sizes, int n_in,
                              void* d_out, int out_size, void* d_ws, size_t ws_size,
                              hipStream_t stream) {
    const float* cw_q     = (const float*)d_in[0];
    const float* codebook = (const float*)d_in[1];
    float* out = (float*)d_out;
    int*   idx = (int*)d_ws;   // 512 KB scratch

    vq_fused_kernel<<<C_DIM * (B_DIM / 32), 256, 0, stream>>>(cw_q, codebook, out, idx);
    vq_scatter_ones<<<(B_DIM * C_DIM) / 256, 256, 0, stream>>>(idx, out);
}

// Round 16
// 147.874 us; speedup vs baseline: 1.0896x; 1.0717x over previous
//
#include <hip/hip_runtime.h>

// Problem shapes (fixed by reference setup_inputs)
#define B_DIM 1024
#define C_DIM 128
#define K_DIM 1024
#define E_DIM 4
#define EMBED_ELEMS (B_DIM * C_DIM * E_DIM)
#define NROWS (B_DIM * C_DIM)

typedef float f32x4 __attribute__((ext_vector_type(4)));

// f32 screen: worst-case |d32 - d64| <= ~1e-4; order flip requires f32 gap
// <= 2e-4. THR = 1e-3 gives 5x margin; flagged rows get the exact f64 pass.
#define SCREEN_THR 1e-3f

// d_ws layout: [0] = atomic counter; +4096 B: idx[NROWS]; then list[NROWS].
#define WS_IDX_OFF 1024          // in ints
#define WS_LIST_OFF (1024 + NROWS)

__global__ void vq_init(int* ws) { ws[0] = 0; }

// ---------------------------------------------------------------------------
// K_screen: f32 top-2 screen + embed/idx + paced 128 KB/block zero-fill.
// Ambiguous rows appended to fixup list (no f64 in this kernel -> low VGPR,
// high occupancy -> waves cover each other's store-queue stalls).
// Grid = 4096 blocks.
// ---------------------------------------------------------------------------
__global__ __launch_bounds__(256) void vq_screen_kernel(
    const float* __restrict__ cw_q,      // (B, C*E) f32
    const float* __restrict__ codebook,  // (C, K, E) f32
    float* __restrict__ out,             // [embed | one_hot]
    int* __restrict__ ws)                // counter / idx / list
{
    __shared__ float4 lds_cb[K_DIM];     // 16 KB: codebook[c]

    const int lane = threadIdx.x & 63;
    const int wave = threadIdx.x >> 6;
    const int bid  = blockIdx.x;
    const int c      = bid >> 5;         // 32 blocks per c
    const int btile  = bid & 31;
    const int b_base = btile * 32 + wave * 8;

    const float4* cb4 = (const float4*)codebook + (size_t)c * K_DIM;
    const float4* x4  = (const float4*)cw_q;    // (B, C) float4
    float4* emb4 = (float4*)out;                // (B, C) float4
    int* idx_out = ws + WS_IDX_OFF;
    int* list    = ws + WS_LIST_OFF;

    // Zero-fill destination: 128 KB contiguous per block.
    f32x4* zdst = (f32x4*)(out + EMBED_ELEMS) + (size_t)bid * 8192
                + threadIdx.x;
    const f32x4 zval = {0.f, 0.f, 0.f, 0.f};

    for (int t = threadIdx.x; t < K_DIM; t += 256)
        lds_cb[t] = cb4[t];
    float4 xr[8];
#pragma unroll
    for (int i = 0; i < 8; ++i)
        xr[i] = x4[(size_t)(b_base + i) * C_DIM + c];
    __syncthreads();

    // Per-lane ||b_k||^2 in f32, hoisted.
    float bsqf[16];
#pragma unroll
    for (int j = 0; j < 16; ++j) {
        const float4 cb = lds_cb[j * 64 + lane];
        bsqf[j] = cb.x * cb.x + cb.y * cb.y + cb.z * cb.z + cb.w * cb.w;
    }

    for (int g = 0; g < 2; ++g) {
        float x2f[4][4];
#pragma unroll
        for (int ii = 0; ii < 4; ++ii) {
            const float4 x = xr[g * 4 + ii];
            x2f[ii][0] = -2.0f * x.x;  x2f[ii][1] = -2.0f * x.y;
            x2f[ii][2] = -2.0f * x.z;  x2f[ii][3] = -2.0f * x.w;
        }

        float b1[4], b2[4];  int k1[4];
#pragma unroll
        for (int ii = 0; ii < 4; ++ii) { b1[ii] = INFINITY; b2[ii] = INFINITY; k1[ii] = 0x7fffffff; }

        float4 cbn = lds_cb[lane];
#pragma unroll 1   // keep one store per iteration — do NOT re-cluster
        for (int j = 0; j < 16; ++j) {
            const float4 cb = cbn;
            if (j < 15) cbn = lds_cb[(j + 1) * 64 + lane];
            zdst[(g * 16 + j) * 256] = zval;   // paced slot g*16+j of 32

            const float bsqj = bsqf[j];
            const int k = j * 64 + lane;
#pragma unroll
            for (int ii = 0; ii < 4; ++ii) {
                const float d = fmaf(cb.w, x2f[ii][3],
                                fmaf(cb.z, x2f[ii][2],
                                fmaf(cb.y, x2f[ii][1],
                                fmaf(cb.x, x2f[ii][0], bsqj))));
                const bool  lt1  = d < b1[ii];
                const float old1 = b1[ii];
                b1[ii] = lt1 ? d : old1;
                k1[ii] = lt1 ? k : k1[ii];
                b2[ii] = lt1 ? old1 : fminf(b2[ii], d);
            }
        }

        // Butterfly: global top-2 values + argmin index (32-bit ops).
#pragma unroll
        for (int off = 32; off >= 1; off >>= 1) {
#pragma unroll
            for (int ii = 0; ii < 4; ++ii) {
                const float ob1 = __shfl_xor(b1[ii], off);
                const int   ok1 = __shfl_xor(k1[ii], off);
                const float ob2 = __shfl_xor(b2[ii], off);
                const float mx  = fmaxf(b1[ii], ob1);
                b2[ii] = fminf(mx, fminf(b2[ii], ob2));
                if (ob1 < b1[ii] || (ob1 == b1[ii] && ok1 < k1[ii])) {
                    b1[ii] = ob1; k1[ii] = ok1;
                }
            }
        }

        // Provisional writes; ambiguous rows -> fixup list (~1%).
#pragma unroll
        for (int ii = 0; ii < 4; ++ii) {
            const int b  = b_base + g * 4 + ii;
            const int fk = k1[ii];
            const int r  = b * C_DIM + c;
            if (lane == 0) {
                emb4[r]    = lds_cb[fk];
                idx_out[r] = fk;
                if (!(b2[ii] - b1[ii] > SCREEN_THR)) {
                    const int p = atomicAdd(ws, 1);
                    list[p] = r;
                }
            }
        }
    }
}

// ---------------------------------------------------------------------------
// K_fix: exact f64 re-solve for flagged rows. One wave per row, wave-stride.
// Codebook read from global (L2-resident). Bit-identical to R3-proven path.
// ---------------------------------------------------------------------------
__global__ __launch_bounds__(256) void vq_fix_kernel(
    const float* __restrict__ cw_q,
    const float* __restrict__ codebook,
    float* __restrict__ out,
    int* __restrict__ ws)
{
    const int lane = threadIdx.x & 63;
    const int wave = threadIdx.x >> 6;
    const int n    = ws[0];
    const int* list = ws + WS_LIST_OFF;
    int* idx_out    = ws + WS_IDX_OFF;
    const float4* x4 = (const float4*)cw_q;
    float4* emb4     = (float4*)out;

    for (int w = blockIdx.x * 4 + wave; w < n; w += gridDim.x * 4) {
        const int r = list[w];
        const int c = r & (C_DIM - 1);
        const float4* cb4 = (const float4*)codebook + (size_t)c * K_DIM;

        const float4 x = x4[r];
        const double x20 = -2.0 * (double)x.x;
        const double x21 = -2.0 * (double)x.y;
        const double x22 = -2.0 * (double)x.z;
        const double x23 = -2.0 * (double)x.w;

        double bd = INFINITY;  int bk = 0x7fffffff;
        for (int j = 0; j < 16; ++j) {
            const float4 cb = cb4[j * 64 + lane];
            const double bx = (double)cb.x, by = (double)cb.y,
                         bz = (double)cb.z, bw = (double)cb.w;
            const double bsqj = bx * bx + by * by + bz * bz + bw * bw;
            const double d = fma(bw, x23, fma(bz, x22,
                             fma(by, x21, fma(bx, x20, bsqj))));
            const int k = j * 64 + lane;
            if (d < bd) { bd = d; bk = k; }
        }
#pragma unroll
        for (int off = 32; off >= 1; off >>= 1) {
            const double od = __shfl_xor(bd, off);
            const int    oi = __shfl_xor(bk, off);
            if (od < bd || (od == bd && oi < bk)) { bd = od; bk = oi; }
        }
        if (lane == 0) {
            emb4[r]    = cb4[bk];
            idx_out[r] = bk;
        }
    }
}

// ---------------------------------------------------------------------------
// K_ones: scatter the 131072 ones (reads final idx, after K_fix).
// ---------------------------------------------------------------------------
__global__ __launch_bounds__(256) void vq_scatter_ones(
    const int* __restrict__ ws,
    float* __restrict__ out)
{
    const int r = blockIdx.x * 256 + threadIdx.x;
    const int k = (ws + WS_IDX_OFF)[r];
    out[EMBED_ELEMS + (size_t)r * K_DIM + k] = 1.0f;
}

extern "C" void kernel_launch(void* const* d_in, const int* in_sizes, int n_in,
                              void* d_out, int out_size, void* d_ws, size_t ws_size,
                              hipStream_t stream) {
    const float* cw_q     = (const float*)d_in[0];
    const float* codebook = (const float*)d_in[1];
    float* out = (float*)d_out;
    int*   ws  = (int*)d_ws;

    vq_init<<<1, 1, 0, stream>>>(ws);
    vq_screen_kernel<<<C_DIM * (B_DIM / 32), 256, 0, stream>>>(cw_q, codebook, out, ws);
    vq_fix_kernel<<<256, 256, 0, stream>>>(cw_q, codebook, out, ws);
    vq_scatter_ones<<<NROWS / 256, 256, 0, stream>>>(ws, out);
}